// Round 3
// baseline (115.847 us; speedup 1.0000x reference)
//
#include <hip/hip_runtime.h>
#include <math.h>

#define NB 32      // BF
#define NW 32      // WIDTH
#define ND 3
#define PS 264     // per-stage float stride: 32 units * 8 floats + S at [256] (+pad)
#define PPT 8      // points per thread
#define NPAIR (PPT/2)

typedef float v2f __attribute__((ext_vector_type(2)));

// Per-stage packed params, per hidden unit w (8 floats, 16B-aligned pairs):
//   [0..2] = W[w][0..2] / 3        (poly-tanh uses w = arg/3, clamped to [-1,1])
//   [3]    = Bb[w] / 3
//   [4..6] = U''[w][0..2] = U*sigmoid(G)/32
//   [7]    = s'[w] = (1/32) * sum_d W[w][d]*(U*sigmoid(G))[w][d]
// o[256] = S' = sum_w s'[w]

__global__ void hyper_kernel(const float* __restrict__ w1, const float* __restrict__ b1,
                             const float* __restrict__ w2, const float* __restrict__ b2,
                             const float* __restrict__ wW, const float* __restrict__ bW,
                             const float* __restrict__ wU, const float* __restrict__ bU,
                             const float* __restrict__ wG, const float* __restrict__ bG,
                             const float* __restrict__ wB, const float* __restrict__ bB,
                             float* __restrict__ ws) {
  const int stage = blockIdx.x;
  const float tv[8] = {2.f, 1.5f, 1.5f, 1.f, 1.f, 0.5f, 0.5f, 0.f};
  const float t = tv[stage];
  __shared__ float h1[NB], h2[NB];
  __shared__ float Wl[NW*ND], Ul[NW*ND], Gl[NW*ND], UUl[NW*ND], Bbl[NW], sl[NW];
  const int tid = threadIdx.x;

  if (tid < NB) h1[tid] = tanhf(t * w1[tid] + b1[tid]);
  __syncthreads();
  if (tid < NB) {
    float a = b2[tid];
    for (int j = 0; j < NB; ++j) a = fmaf(w2[tid*NB + j], h1[j], a);
    h2[tid] = tanhf(a);
  }
  __syncthreads();
  for (int idx = tid; idx < 3*NW*ND + NW; idx += blockDim.x) {
    if (idx < 96) {
      float a = bW[idx];
      for (int j = 0; j < NB; ++j) a = fmaf(wW[idx*NB + j], h2[j], a);
      Wl[idx] = a;
    } else if (idx < 192) {
      int i = idx - 96; float a = bU[i];
      for (int j = 0; j < NB; ++j) a = fmaf(wU[i*NB + j], h2[j], a);
      Ul[i] = a;
    } else if (idx < 288) {
      int i = idx - 192; float a = bG[i];
      for (int j = 0; j < NB; ++j) a = fmaf(wG[i*NB + j], h2[j], a);
      Gl[i] = a;
    } else {
      int i = idx - 288; float a = bB[i];
      for (int j = 0; j < NB; ++j) a = fmaf(wB[i*NB + j], h2[j], a);
      Bbl[i] = a;
    }
  }
  __syncthreads();
  for (int idx = tid; idx < NW*ND; idx += blockDim.x)
    UUl[idx] = Ul[idx] / (1.f + expf(-Gl[idx]));
  __syncthreads();

  float* o = ws + stage * PS;
  const float inv = 1.f / 32.f;
  const float i3  = 1.f / 3.f;
  if (tid < NW) {
    const int w = tid;
    float s = Wl[3*w+0]*UUl[3*w+0] + Wl[3*w+1]*UUl[3*w+1] + Wl[3*w+2]*UUl[3*w+2];
    sl[w] = s;
    o[w*8+0] = i3 * Wl[3*w+0];
    o[w*8+1] = i3 * Wl[3*w+1];
    o[w*8+2] = i3 * Wl[3*w+2];
    o[w*8+3] = i3 * Bbl[w];
    o[w*8+4] = inv * UUl[3*w+0];
    o[w*8+5] = inv * UUl[3*w+1];
    o[w*8+6] = inv * UUl[3*w+2];
    o[w*8+7] = inv * s;
  }
  __syncthreads();
  if (tid == 0) {
    float S = 0.f;
    for (int w = 0; w < NW; ++w) S += sl[w];
    o[256] = inv * S;
  }
}

__device__ __forceinline__ v2f bc(float s) { v2f r; r[0] = s; r[1] = s; return r; }
__device__ __forceinline__ v2f vfma(v2f a, v2f b, v2f c) { return __builtin_elementwise_fma(a, b, c); }
__device__ __forceinline__ v2f vmaxv(v2f a, v2f b) { return __builtin_elementwise_max(a, b); }
__device__ __forceinline__ v2f vminv(v2f a, v2f b) { return __builtin_elementwise_min(a, b); }

// one func() eval for PPT points (NPAIR float2 pairs); poly tanh h = w*Q(w^2), w=clamp(arg/3)
__device__ __forceinline__ void feval8(const float* __restrict__ p,
                                       const v2f zx[NPAIR], const v2f zy[NPAIR], const v2f zz[NPAIR],
                                       v2f kx[NPAIR], v2f ky[NPAIR], v2f kz[NPAIR], v2f tr[NPAIR],
                                       float c0, float c1, float c2, float c3,
                                       float c4, float c5, float c6, float c7) {
  v2f ax[NPAIR], ay[NPAIR], az[NPAIR], a2[NPAIR];
#pragma unroll
  for (int j = 0; j < NPAIR; ++j) { ax[j]=bc(0.f); ay[j]=bc(0.f); az[j]=bc(0.f); a2[j]=bc(0.f); }
  const float S = p[256];
#pragma unroll 4
  for (int w = 0; w < NW; ++w) {
    const float4 A  = *reinterpret_cast<const float4*>(p + w*8);      // W/3, Bb/3
    const float4 Bv = *reinterpret_cast<const float4*>(p + w*8 + 4);  // U'', s'
#pragma unroll
    for (int j = 0; j < NPAIR; ++j) {
      v2f wv = vfma(zx[j], bc(A.x), vfma(zy[j], bc(A.y), vfma(zz[j], bc(A.z), bc(A.w))));
      wv = vminv(vmaxv(wv, bc(-1.f)), bc(1.f));
      v2f t = wv * wv;
      v2f P = bc(c7);
      P = vfma(P, t, bc(c6));
      P = vfma(P, t, bc(c5));
      P = vfma(P, t, bc(c4));
      P = vfma(P, t, bc(c3));
      P = vfma(P, t, bc(c2));
      P = vfma(P, t, bc(c1));
      P = vfma(P, t, bc(c0));
      v2f h = wv * P;
      v2f hh = h * h;
      ax[j] = vfma(h,  bc(Bv.x), ax[j]);
      ay[j] = vfma(h,  bc(Bv.y), ay[j]);
      az[j] = vfma(h,  bc(Bv.z), az[j]);
      a2[j] = vfma(hh, bc(Bv.w), a2[j]);
    }
  }
#pragma unroll
  for (int j = 0; j < NPAIR; ++j) {
    kx[j] = ax[j]; ky[j] = ay[j]; kz[j] = az[j];
    tr[j] = bc(S) - a2[j];
  }
}

__global__ __launch_bounds__(256) void ffjord_main(const float* __restrict__ z1,
                                                   const float* __restrict__ ws,
                                                   float* __restrict__ out, int n,
                                                   float c0, float c1, float c2, float c3,
                                                   float c4, float c5, float c6, float c7) {
  __shared__ __align__(16) float sp[8*PS];
  for (int i = threadIdx.x; i < 8*PS; i += 256) sp[i] = ws[i];
  __syncthreads();

  const int base = blockIdx.x * (256*PPT) + threadIdx.x;
  v2f zx[NPAIR], zy[NPAIR], zz[NPAIR], ld[NPAIR];
  bool val[PPT];
#pragma unroll
  for (int j = 0; j < PPT; ++j) {
    int i = base + j*256;
    val[j] = (i < n);
    int ii = val[j] ? i : 0;
    zx[j>>1][j&1] = z1[3*ii+0];
    zy[j>>1][j&1] = z1[3*ii+1];
    zz[j>>1][j&1] = z1[3*ii+2];
  }
#pragma unroll
  for (int j = 0; j < NPAIR; ++j) ld[j] = bc(0.f);

  for (int itv = 0; itv < 2; ++itv) {
    const float* b0 = sp + itv*4*PS;
    v2f kx[NPAIR], ky[NPAIR], kz[NPAIR], kt[NPAIR];
    v2f accx[NPAIR], accy[NPAIR], accz[NPAIR], acct[NPAIR];
    v2f yx[NPAIR], yy[NPAIR], yz[NPAIR];

    feval8(b0, zx, zy, zz, kx, ky, kz, kt, c0,c1,c2,c3,c4,c5,c6,c7);
#pragma unroll
    for (int j = 0; j < NPAIR; ++j) {
      accx[j]=kx[j]; accy[j]=ky[j]; accz[j]=kz[j]; acct[j]=kt[j];
      yx[j]=vfma(bc(-0.5f),kx[j],zx[j]); yy[j]=vfma(bc(-0.5f),ky[j],zy[j]); yz[j]=vfma(bc(-0.5f),kz[j],zz[j]);
    }
    feval8(b0 + PS, yx, yy, yz, kx, ky, kz, kt, c0,c1,c2,c3,c4,c5,c6,c7);
#pragma unroll
    for (int j = 0; j < NPAIR; ++j) {
      accx[j]=vfma(bc(2.f),kx[j],accx[j]); accy[j]=vfma(bc(2.f),ky[j],accy[j]);
      accz[j]=vfma(bc(2.f),kz[j],accz[j]); acct[j]=vfma(bc(2.f),kt[j],acct[j]);
      yx[j]=vfma(bc(-0.5f),kx[j],zx[j]); yy[j]=vfma(bc(-0.5f),ky[j],zy[j]); yz[j]=vfma(bc(-0.5f),kz[j],zz[j]);
    }
    feval8(b0 + 2*PS, yx, yy, yz, kx, ky, kz, kt, c0,c1,c2,c3,c4,c5,c6,c7);
#pragma unroll
    for (int j = 0; j < NPAIR; ++j) {
      accx[j]=vfma(bc(2.f),kx[j],accx[j]); accy[j]=vfma(bc(2.f),ky[j],accy[j]);
      accz[j]=vfma(bc(2.f),kz[j],accz[j]); acct[j]=vfma(bc(2.f),kt[j],acct[j]);
      yx[j]=zx[j]-kx[j]; yy[j]=zy[j]-ky[j]; yz[j]=zz[j]-kz[j];
    }
    feval8(b0 + 3*PS, yx, yy, yz, kx, ky, kz, kt, c0,c1,c2,c3,c4,c5,c6,c7);
    const v2f c6th = bc(1.f/6.f);
#pragma unroll
    for (int j = 0; j < NPAIR; ++j) {
      zx[j] = vfma(-c6th, accx[j]+kx[j], zx[j]);
      zy[j] = vfma(-c6th, accy[j]+ky[j], zy[j]);
      zz[j] = vfma(-c6th, accz[j]+kz[j], zz[j]);
      ld[j] = vfma(-c6th, acct[j]+kt[j], ld[j]);
    }
  }

#pragma unroll
  for (int j = 0; j < PPT; ++j) {
    if (val[j]) {
      int i = base + j*256;
      out[3*i+0] = zx[j>>1][j&1];
      out[3*i+1] = zy[j>>1][j&1];
      out[3*i+2] = zz[j>>1][j&1];
      out[3*n + i] = ld[j>>1][j&1];
    }
  }
}

extern "C" void kernel_launch(void* const* d_in, const int* in_sizes, int n_in,
                              void* d_out, int out_size, void* d_ws, size_t ws_size,
                              hipStream_t stream) {
  const float* z1 = (const float*)d_in[0];
  const float* w1 = (const float*)d_in[1];
  const float* b1 = (const float*)d_in[2];
  const float* w2 = (const float*)d_in[3];
  const float* b2 = (const float*)d_in[4];
  const float* wW = (const float*)d_in[5];
  const float* bW = (const float*)d_in[6];
  const float* wU = (const float*)d_in[7];
  const float* bU = (const float*)d_in[8];
  const float* wG = (const float*)d_in[9];
  const float* bG = (const float*)d_in[10];
  const float* wB = (const float*)d_in[11];
  const float* bB = (const float*)d_in[12];
  float* out = (float*)d_out;
  float* ws  = (float*)d_ws;
  const int n = in_sizes[0] / 3;

  // Host-side: degree-7 Chebyshev interpolation (in t = w^2 on [0,1]) of
  // Q(t) = tanh(3*sqrt(t))/sqrt(t), so device tanh(x) ~= w*Q(w^2), w = clamp(x/3, -1, 1).
  double u[8], fv[8];
  for (int k = 0; k < 8; ++k) {
    u[k] = 0.5 + 0.5 * cos((2.0*k + 1.0) * M_PI / 16.0);
    double wr = sqrt(u[k]);
    fv[k] = tanh(3.0 * wr) / wr;
  }
  double mono[8] = {0,0,0,0,0,0,0,0};
  for (int k = 0; k < 8; ++k) {
    double pl[8] = {1,0,0,0,0,0,0,0};
    int deg = 0;
    double den = 1.0;
    for (int m = 0; m < 8; ++m) {
      if (m == k) continue;
      for (int i = deg+1; i >= 1; --i) pl[i] = pl[i-1] - u[m]*pl[i];
      pl[0] = -u[m]*pl[0];
      ++deg;
      den *= (u[k] - u[m]);
    }
    double s = fv[k] / den;
    for (int i = 0; i < 8; ++i) mono[i] += s * pl[i];
  }
  float cf[8];
  for (int i = 0; i < 8; ++i) cf[i] = (float)mono[i];

  hipLaunchKernelGGL(hyper_kernel, dim3(8), dim3(128), 0, stream,
                     w1, b1, w2, b2, wW, bW, wU, bU, wG, bG, wB, bB, ws);
  const int blocks = (n + 256*PPT - 1) / (256*PPT);
  hipLaunchKernelGGL(ffjord_main, dim3(blocks), dim3(256), 0, stream,
                     z1, ws, out, n,
                     cf[0], cf[1], cf[2], cf[3], cf[4], cf[5], cf[6], cf[7]);
}

// Round 4
// 103.832 us; speedup vs baseline: 1.1157x; 1.1157x over previous
//
#include <hip/hip_runtime.h>
#include <math.h>

#define NB 32      // BF
#define NW 32      // WIDTH
#define ND 3
#define PS 264     // per-stage float stride: 32 units * 8 floats + S at [256] (+pad)
#define PPT 4      // points per thread

// Per-stage packed params, per hidden unit w (8 floats, 16B aligned):
//   [0..2] = W[w][0..2] / 3        (poly-tanh uses w = clamp(arg/3, -1, 1))
//   [3]    = Bb[w] / 3
//   [4..6] = U''[w][0..2] = U*sigmoid(G)/32
//   [7]    = s'[w] = (1/32) * sum_d W[w][d]*(U*sigmoid(G))[w][d]
// o[256] = S' = sum_w s'[w]

__global__ void hyper_kernel(const float* __restrict__ w1, const float* __restrict__ b1,
                             const float* __restrict__ w2, const float* __restrict__ b2,
                             const float* __restrict__ wW, const float* __restrict__ bW,
                             const float* __restrict__ wU, const float* __restrict__ bU,
                             const float* __restrict__ wG, const float* __restrict__ bG,
                             const float* __restrict__ wB, const float* __restrict__ bB,
                             float* __restrict__ ws) {
  const int stage = blockIdx.x;
  const float tv[8] = {2.f, 1.5f, 1.5f, 1.f, 1.f, 0.5f, 0.5f, 0.f};
  const float t = tv[stage];
  __shared__ float h1[NB], h2[NB];
  __shared__ float Wl[NW*ND], Ul[NW*ND], Gl[NW*ND], UUl[NW*ND], Bbl[NW], sl[NW];
  const int tid = threadIdx.x;

  if (tid < NB) h1[tid] = tanhf(t * w1[tid] + b1[tid]);
  __syncthreads();
  if (tid < NB) {
    float a = b2[tid];
    for (int j = 0; j < NB; ++j) a = fmaf(w2[tid*NB + j], h1[j], a);
    h2[tid] = tanhf(a);
  }
  __syncthreads();
  for (int idx = tid; idx < 3*NW*ND + NW; idx += blockDim.x) {
    if (idx < 96) {
      float a = bW[idx];
      for (int j = 0; j < NB; ++j) a = fmaf(wW[idx*NB + j], h2[j], a);
      Wl[idx] = a;
    } else if (idx < 192) {
      int i = idx - 96; float a = bU[i];
      for (int j = 0; j < NB; ++j) a = fmaf(wU[i*NB + j], h2[j], a);
      Ul[i] = a;
    } else if (idx < 288) {
      int i = idx - 192; float a = bG[i];
      for (int j = 0; j < NB; ++j) a = fmaf(wG[i*NB + j], h2[j], a);
      Gl[i] = a;
    } else {
      int i = idx - 288; float a = bB[i];
      for (int j = 0; j < NB; ++j) a = fmaf(wB[i*NB + j], h2[j], a);
      Bbl[i] = a;
    }
  }
  __syncthreads();
  for (int idx = tid; idx < NW*ND; idx += blockDim.x)
    UUl[idx] = Ul[idx] / (1.f + expf(-Gl[idx]));
  __syncthreads();

  float* o = ws + stage * PS;
  const float inv = 1.f / 32.f;
  const float i3  = 1.f / 3.f;
  if (tid < NW) {
    const int w = tid;
    float s = Wl[3*w+0]*UUl[3*w+0] + Wl[3*w+1]*UUl[3*w+1] + Wl[3*w+2]*UUl[3*w+2];
    sl[w] = s;
    o[w*8+0] = i3 * Wl[3*w+0];
    o[w*8+1] = i3 * Wl[3*w+1];
    o[w*8+2] = i3 * Wl[3*w+2];
    o[w*8+3] = i3 * Bbl[w];
    o[w*8+4] = inv * UUl[3*w+0];
    o[w*8+5] = inv * UUl[3*w+1];
    o[w*8+6] = inv * UUl[3*w+2];
    o[w*8+7] = inv * s;
  }
  __syncthreads();
  if (tid == 0) {
    float S = 0.f;
    for (int w = 0; w < NW; ++w) S += sl[w];
    o[256] = inv * S;
  }
}

// clamp(x,-1,1) in one VALU op (inline consts are free in VOP3)
__device__ __forceinline__ float med3_pm1(float x) {
  float r;
  asm("v_med3_f32 %0, %1, -1.0, 1.0" : "=v"(r) : "v"(x));
  return r;
}

// one func() eval for PPT points; tanh(x) ~= w*Q(w^2), w = clamp(x/3,-1,1),
// Q = deg-6 Chebyshev interpolant (host-computed), coeffs in SGPRs (kernel args)
__device__ __forceinline__ void feval4(const float* __restrict__ p,
                                       const float zx[PPT], const float zy[PPT], const float zz[PPT],
                                       float kx[PPT], float ky[PPT], float kz[PPT], float tr[PPT],
                                       float c0, float c1, float c2, float c3,
                                       float c4, float c5, float c6) {
  float ax[PPT], ay[PPT], az[PPT], a2[PPT];
#pragma unroll
  for (int j = 0; j < PPT; ++j) { ax[j]=0.f; ay[j]=0.f; az[j]=0.f; a2[j]=0.f; }
  const float S = p[256];
#pragma unroll 8
  for (int w = 0; w < NW; ++w) {
    const float4 A  = *reinterpret_cast<const float4*>(p + w*8);      // W/3, Bb/3
    const float4 Bv = *reinterpret_cast<const float4*>(p + w*8 + 4);  // U'', s'
#pragma unroll
    for (int j = 0; j < PPT; ++j) {
      float wv = fmaf(zx[j], A.x, fmaf(zy[j], A.y, fmaf(zz[j], A.z, A.w)));
      wv = med3_pm1(wv);
      float t = wv * wv;
      float P = fmaf(c6, t, c5);
      P = fmaf(P, t, c4);
      P = fmaf(P, t, c3);
      P = fmaf(P, t, c2);
      P = fmaf(P, t, c1);
      P = fmaf(P, t, c0);
      float h = wv * P;
      ax[j] = fmaf(h, Bv.x, ax[j]);
      ay[j] = fmaf(h, Bv.y, ay[j]);
      az[j] = fmaf(h, Bv.z, az[j]);
      a2[j] = fmaf(h*h, Bv.w, a2[j]);
    }
  }
#pragma unroll
  for (int j = 0; j < PPT; ++j) {
    kx[j] = ax[j]; ky[j] = ay[j]; kz[j] = az[j];
    tr[j] = S - a2[j];
  }
}

__global__ __launch_bounds__(256) void ffjord_main(const float* __restrict__ z1,
                                                   const float* __restrict__ ws,
                                                   float* __restrict__ out, int n,
                                                   float c0, float c1, float c2, float c3,
                                                   float c4, float c5, float c6) {
  __shared__ __align__(16) float sp[8*PS];
  for (int i = threadIdx.x; i < 8*PS; i += 256) sp[i] = ws[i];
  __syncthreads();

  const int base = blockIdx.x * (256*PPT) + threadIdx.x;
  float zx[PPT], zy[PPT], zz[PPT], ld[PPT];
  bool val[PPT];
#pragma unroll
  for (int j = 0; j < PPT; ++j) {
    int i = base + j*256;
    val[j] = (i < n);
    int ii = val[j] ? i : 0;
    zx[j] = z1[3*ii+0]; zy[j] = z1[3*ii+1]; zz[j] = z1[3*ii+2];
    ld[j] = 0.f;
  }

  for (int itv = 0; itv < 2; ++itv) {
    const float* b0 = sp + itv*4*PS;
    float kx[PPT], ky[PPT], kz[PPT], kt[PPT];
    float accx[PPT], accy[PPT], accz[PPT], acct[PPT];
    float yx[PPT], yy[PPT], yz[PPT];

    feval4(b0, zx, zy, zz, kx, ky, kz, kt, c0,c1,c2,c3,c4,c5,c6);
#pragma unroll
    for (int j = 0; j < PPT; ++j) {
      accx[j]=kx[j]; accy[j]=ky[j]; accz[j]=kz[j]; acct[j]=kt[j];
      yx[j]=fmaf(-0.5f,kx[j],zx[j]); yy[j]=fmaf(-0.5f,ky[j],zy[j]); yz[j]=fmaf(-0.5f,kz[j],zz[j]);
    }
    feval4(b0 + PS, yx, yy, yz, kx, ky, kz, kt, c0,c1,c2,c3,c4,c5,c6);
#pragma unroll
    for (int j = 0; j < PPT; ++j) {
      accx[j]=fmaf(2.f,kx[j],accx[j]); accy[j]=fmaf(2.f,ky[j],accy[j]);
      accz[j]=fmaf(2.f,kz[j],accz[j]); acct[j]=fmaf(2.f,kt[j],acct[j]);
      yx[j]=fmaf(-0.5f,kx[j],zx[j]); yy[j]=fmaf(-0.5f,ky[j],zy[j]); yz[j]=fmaf(-0.5f,kz[j],zz[j]);
    }
    feval4(b0 + 2*PS, yx, yy, yz, kx, ky, kz, kt, c0,c1,c2,c3,c4,c5,c6);
#pragma unroll
    for (int j = 0; j < PPT; ++j) {
      accx[j]=fmaf(2.f,kx[j],accx[j]); accy[j]=fmaf(2.f,ky[j],accy[j]);
      accz[j]=fmaf(2.f,kz[j],accz[j]); acct[j]=fmaf(2.f,kt[j],acct[j]);
      yx[j]=zx[j]-kx[j]; yy[j]=zy[j]-ky[j]; yz[j]=zz[j]-kz[j];
    }
    feval4(b0 + 3*PS, yx, yy, yz, kx, ky, kz, kt, c0,c1,c2,c3,c4,c5,c6);
    const float c = 1.f / 6.f;
#pragma unroll
    for (int j = 0; j < PPT; ++j) {
      zx[j] -= c * (accx[j] + kx[j]);
      zy[j] -= c * (accy[j] + ky[j]);
      zz[j] -= c * (accz[j] + kz[j]);
      ld[j] -= c * (acct[j] + kt[j]);
    }
  }

#pragma unroll
  for (int j = 0; j < PPT; ++j) {
    if (val[j]) {
      int i = base + j*256;
      out[3*i+0] = zx[j]; out[3*i+1] = zy[j]; out[3*i+2] = zz[j];
      out[3*n + i] = ld[j];
    }
  }
}

extern "C" void kernel_launch(void* const* d_in, const int* in_sizes, int n_in,
                              void* d_out, int out_size, void* d_ws, size_t ws_size,
                              hipStream_t stream) {
  const float* z1 = (const float*)d_in[0];
  const float* w1 = (const float*)d_in[1];
  const float* b1 = (const float*)d_in[2];
  const float* w2 = (const float*)d_in[3];
  const float* b2 = (const float*)d_in[4];
  const float* wW = (const float*)d_in[5];
  const float* bW = (const float*)d_in[6];
  const float* wU = (const float*)d_in[7];
  const float* bU = (const float*)d_in[8];
  const float* wG = (const float*)d_in[9];
  const float* bG = (const float*)d_in[10];
  const float* wB = (const float*)d_in[11];
  const float* bB = (const float*)d_in[12];
  float* out = (float*)d_out;
  float* ws  = (float*)d_ws;
  const int n = in_sizes[0] / 3;

  // Host: deg-6 Chebyshev interpolation (in t = w^2 on [0,1]) of
  // Q(t) = tanh(3*sqrt(t))/sqrt(t); device tanh(x) ~= w*Q(w^2), w = clamp(x/3,-1,1).
  const int NC = 7;
  double u[NC], fv[NC];
  for (int k = 0; k < NC; ++k) {
    u[k] = 0.5 + 0.5 * cos((2.0*k + 1.0) * M_PI / (2.0*NC));
    double wr = sqrt(u[k]);
    fv[k] = tanh(3.0 * wr) / wr;
  }
  double mono[NC];
  for (int i = 0; i < NC; ++i) mono[i] = 0.0;
  for (int k = 0; k < NC; ++k) {
    double pl[NC];
    pl[0] = 1.0; for (int i = 1; i < NC; ++i) pl[i] = 0.0;
    int deg = 0;
    double den = 1.0;
    for (int m = 0; m < NC; ++m) {
      if (m == k) continue;
      for (int i = deg+1; i >= 1; --i) pl[i] = pl[i-1] - u[m]*pl[i];
      pl[0] = -u[m]*pl[0];
      ++deg;
      den *= (u[k] - u[m]);
    }
    double s = fv[k] / den;
    for (int i = 0; i < NC; ++i) mono[i] += s * pl[i];
  }
  float cf[NC];
  for (int i = 0; i < NC; ++i) cf[i] = (float)mono[i];

  hipLaunchKernelGGL(hyper_kernel, dim3(8), dim3(128), 0, stream,
                     w1, b1, w2, b2, wW, bW, wU, bU, wG, bG, wB, bB, ws);
  const int blocks = (n + 256*PPT - 1) / (256*PPT);
  hipLaunchKernelGGL(ffjord_main, dim3(blocks), dim3(256), 0, stream,
                     z1, ws, out, n,
                     cf[0], cf[1], cf[2], cf[3], cf[4], cf[5], cf[6]);
}

// Round 5
// 102.975 us; speedup vs baseline: 1.1250x; 1.0083x over previous
//
#include <hip/hip_runtime.h>
#include <math.h>

#define NB 32      // BF
#define NW 32      // WIDTH
#define ND 3
#define PS 264     // per-stage float stride: 32 units * 8 floats + S at [256] (+pad)
#define PPT 4      // points per thread

// Per-stage packed params, per hidden unit w (8 floats, 16B aligned):
//   [0..2] = W[w][0..2] / 3        (poly-tanh uses w = clamp(arg/3, -1, 1))
//   [3]    = Bb[w] / 3
//   [4..6] = U''[w][0..2] = U*sigmoid(G)/32
//   [7]    = s'[w] = (1/32) * sum_d W[w][d]*(U*sigmoid(G))[w][d]
// o[256] = S' = sum_w s'[w]

__global__ void hyper_kernel(const float* __restrict__ w1, const float* __restrict__ b1,
                             const float* __restrict__ w2, const float* __restrict__ b2,
                             const float* __restrict__ wW, const float* __restrict__ bW,
                             const float* __restrict__ wU, const float* __restrict__ bU,
                             const float* __restrict__ wG, const float* __restrict__ bG,
                             const float* __restrict__ wB, const float* __restrict__ bB,
                             float* __restrict__ ws) {
  const int stage = blockIdx.x;
  const float tv[8] = {2.f, 1.5f, 1.5f, 1.f, 1.f, 0.5f, 0.5f, 0.f};
  const float t = tv[stage];
  __shared__ float h1[NB], h2[NB];
  __shared__ float Wl[NW*ND], Ul[NW*ND], Gl[NW*ND], UUl[NW*ND], Bbl[NW], sl[NW];
  const int tid = threadIdx.x;

  if (tid < NB) h1[tid] = tanhf(t * w1[tid] + b1[tid]);
  __syncthreads();
  if (tid < NB) {
    float a = b2[tid];
    for (int j = 0; j < NB; ++j) a = fmaf(w2[tid*NB + j], h1[j], a);
    h2[tid] = tanhf(a);
  }
  __syncthreads();
  for (int idx = tid; idx < 3*NW*ND + NW; idx += blockDim.x) {
    if (idx < 96) {
      float a = bW[idx];
      for (int j = 0; j < NB; ++j) a = fmaf(wW[idx*NB + j], h2[j], a);
      Wl[idx] = a;
    } else if (idx < 192) {
      int i = idx - 96; float a = bU[i];
      for (int j = 0; j < NB; ++j) a = fmaf(wU[i*NB + j], h2[j], a);
      Ul[i] = a;
    } else if (idx < 288) {
      int i = idx - 192; float a = bG[i];
      for (int j = 0; j < NB; ++j) a = fmaf(wG[i*NB + j], h2[j], a);
      Gl[i] = a;
    } else {
      int i = idx - 288; float a = bB[i];
      for (int j = 0; j < NB; ++j) a = fmaf(wB[i*NB + j], h2[j], a);
      Bbl[i] = a;
    }
  }
  __syncthreads();
  for (int idx = tid; idx < NW*ND; idx += blockDim.x)
    UUl[idx] = Ul[idx] / (1.f + expf(-Gl[idx]));
  __syncthreads();

  float* o = ws + stage * PS;
  const float inv = 1.f / 32.f;
  const float i3  = 1.f / 3.f;
  if (tid < NW) {
    const int w = tid;
    float s = Wl[3*w+0]*UUl[3*w+0] + Wl[3*w+1]*UUl[3*w+1] + Wl[3*w+2]*UUl[3*w+2];
    sl[w] = s;
    o[w*8+0] = i3 * Wl[3*w+0];
    o[w*8+1] = i3 * Wl[3*w+1];
    o[w*8+2] = i3 * Wl[3*w+2];
    o[w*8+3] = i3 * Bbl[w];
    o[w*8+4] = inv * UUl[3*w+0];
    o[w*8+5] = inv * UUl[3*w+1];
    o[w*8+6] = inv * UUl[3*w+2];
    o[w*8+7] = inv * s;
  }
  __syncthreads();
  if (tid == 0) {
    float S = 0.f;
    for (int w = 0; w < NW; ++w) S += sl[w];
    o[256] = inv * S;
  }
}

// clamp(x,-1,1) in one VALU op (inline consts are free in VOP3)
__device__ __forceinline__ float med3_pm1(float x) {
  float r;
  asm("v_med3_f32 %0, %1, -1.0, 1.0" : "=v"(r) : "v"(x));
  return r;
}

// one func() eval for PPT points; tanh(x) ~= w*Q(w^2), w = clamp(x/3,-1,1),
// Q = deg-6 Chebyshev interpolant (host-computed), coeffs in SGPRs (kernel args)
__device__ __forceinline__ void feval4(const float* __restrict__ p,
                                       const float zx[PPT], const float zy[PPT], const float zz[PPT],
                                       float kx[PPT], float ky[PPT], float kz[PPT], float tr[PPT],
                                       float c0, float c1, float c2, float c3,
                                       float c4, float c5, float c6) {
  float ax[PPT], ay[PPT], az[PPT], a2[PPT];
#pragma unroll
  for (int j = 0; j < PPT; ++j) { ax[j]=0.f; ay[j]=0.f; az[j]=0.f; a2[j]=0.f; }
  const float S = p[256];
#pragma unroll 8
  for (int w = 0; w < NW; ++w) {
    const float4 A  = *reinterpret_cast<const float4*>(p + w*8);      // W/3, Bb/3
    const float4 Bv = *reinterpret_cast<const float4*>(p + w*8 + 4);  // U'', s'
#pragma unroll
    for (int j = 0; j < PPT; ++j) {
      float wv = fmaf(zx[j], A.x, fmaf(zy[j], A.y, fmaf(zz[j], A.z, A.w)));
      wv = med3_pm1(wv);
      float t = wv * wv;
      float P = fmaf(c6, t, c5);
      P = fmaf(P, t, c4);
      P = fmaf(P, t, c3);
      P = fmaf(P, t, c2);
      P = fmaf(P, t, c1);
      P = fmaf(P, t, c0);
      float h = wv * P;
      ax[j] = fmaf(h, Bv.x, ax[j]);
      ay[j] = fmaf(h, Bv.y, ay[j]);
      az[j] = fmaf(h, Bv.z, az[j]);
      a2[j] = fmaf(h*h, Bv.w, a2[j]);
    }
  }
#pragma unroll
  for (int j = 0; j < PPT; ++j) {
    kx[j] = ax[j]; ky[j] = ay[j]; kz[j] = az[j];
    tr[j] = S - a2[j];
  }
}

__global__ __launch_bounds__(256) void ffjord_main(const float* __restrict__ z1,
                                                   const float* __restrict__ ws,
                                                   float* __restrict__ out, int n,
                                                   float c0, float c1, float c2, float c3,
                                                   float c4, float c5, float c6) {
  __shared__ __align__(16) float sp[8*PS];
  for (int i = threadIdx.x; i < 8*PS; i += 256) sp[i] = ws[i];
  __syncthreads();

  const int base  = blockIdx.x * 256 + threadIdx.x;
  const int pstride = gridDim.x * 256;   // grid-stride over points

  float zx[PPT], zy[PPT], zz[PPT], ld[PPT];
  bool val[PPT];
#pragma unroll
  for (int j = 0; j < PPT; ++j) {
    int i = base + j * pstride;
    val[j] = (i < n);
    int ii = val[j] ? i : 0;
    zx[j] = z1[3*ii+0]; zy[j] = z1[3*ii+1]; zz[j] = z1[3*ii+2];
    ld[j] = 0.f;
  }

  for (int itv = 0; itv < 2; ++itv) {
    float accx[PPT], accy[PPT], accz[PPT], acct[PPT];
    float kx[PPT], ky[PPT], kz[PPT], kt[PPT];
#pragma unroll
    for (int j = 0; j < PPT; ++j) {
      accx[j]=0.f; accy[j]=0.f; accz[j]=0.f; acct[j]=0.f;
      kx[j]=0.f; ky[j]=0.f; kz[j]=0.f;
    }
    // 4 RK4 stages, rolled: y = z + a_s*k_prev; k = f(y); acc += b_s*k
    for (int s = 0; s < 4; ++s) {
      const float as = (s == 0) ? 0.f : ((s == 3) ? -1.f : -0.5f);
      const float bs = (s == 1 || s == 2) ? 2.f : 1.f;
      const float* p = sp + (itv*4 + s) * PS;
      float yx[PPT], yy[PPT], yz[PPT];
#pragma unroll
      for (int j = 0; j < PPT; ++j) {
        yx[j] = fmaf(as, kx[j], zx[j]);
        yy[j] = fmaf(as, ky[j], zy[j]);
        yz[j] = fmaf(as, kz[j], zz[j]);
      }
      feval4(p, yx, yy, yz, kx, ky, kz, kt, c0,c1,c2,c3,c4,c5,c6);
#pragma unroll
      for (int j = 0; j < PPT; ++j) {
        accx[j] = fmaf(bs, kx[j], accx[j]);
        accy[j] = fmaf(bs, ky[j], accy[j]);
        accz[j] = fmaf(bs, kz[j], accz[j]);
        acct[j] = fmaf(bs, kt[j], acct[j]);
      }
    }
    const float c = 1.f / 6.f;
#pragma unroll
    for (int j = 0; j < PPT; ++j) {
      zx[j] -= c * accx[j];
      zy[j] -= c * accy[j];
      zz[j] -= c * accz[j];
      ld[j] -= c * acct[j];
    }
  }

#pragma unroll
  for (int j = 0; j < PPT; ++j) {
    if (val[j]) {
      int i = base + j * pstride;
      out[3*i+0] = zx[j]; out[3*i+1] = zy[j]; out[3*i+2] = zz[j];
      out[3*n + i] = ld[j];
    }
  }
}

extern "C" void kernel_launch(void* const* d_in, const int* in_sizes, int n_in,
                              void* d_out, int out_size, void* d_ws, size_t ws_size,
                              hipStream_t stream) {
  const float* z1 = (const float*)d_in[0];
  const float* w1 = (const float*)d_in[1];
  const float* b1 = (const float*)d_in[2];
  const float* w2 = (const float*)d_in[3];
  const float* b2 = (const float*)d_in[4];
  const float* wW = (const float*)d_in[5];
  const float* bW = (const float*)d_in[6];
  const float* wU = (const float*)d_in[7];
  const float* bU = (const float*)d_in[8];
  const float* wG = (const float*)d_in[9];
  const float* bG = (const float*)d_in[10];
  const float* wB = (const float*)d_in[11];
  const float* bB = (const float*)d_in[12];
  float* out = (float*)d_out;
  float* ws  = (float*)d_ws;
  const int n = in_sizes[0] / 3;

  // Host: deg-6 Chebyshev interpolation (in t = w^2 on [0,1]) of
  // Q(t) = tanh(3*sqrt(t))/sqrt(t); device tanh(x) ~= w*Q(w^2), w = clamp(x/3,-1,1).
  const int NC = 7;
  double u[NC], fv[NC];
  for (int k = 0; k < NC; ++k) {
    u[k] = 0.5 + 0.5 * cos((2.0*k + 1.0) * M_PI / (2.0*NC));
    double wr = sqrt(u[k]);
    fv[k] = tanh(3.0 * wr) / wr;
  }
  double mono[NC];
  for (int i = 0; i < NC; ++i) mono[i] = 0.0;
  for (int k = 0; k < NC; ++k) {
    double pl[NC];
    pl[0] = 1.0; for (int i = 1; i < NC; ++i) pl[i] = 0.0;
    int deg = 0;
    double den = 1.0;
    for (int m = 0; m < NC; ++m) {
      if (m == k) continue;
      for (int i = deg+1; i >= 1; --i) pl[i] = pl[i-1] - u[m]*pl[i];
      pl[0] = -u[m]*pl[0];
      ++deg;
      den *= (u[k] - u[m]);
    }
    double s = fv[k] / den;
    for (int i = 0; i < NC; ++i) mono[i] += s * pl[i];
  }
  float cf[NC];
  for (int i = 0; i < NC; ++i) cf[i] = (float)mono[i];

  hipLaunchKernelGGL(hyper_kernel, dim3(8), dim3(128), 0, stream,
                     w1, b1, w2, b2, wW, bW, wU, bU, wG, bG, wB, bB, ws);
  // round block count up to a multiple of 256 CUs for balance (977 -> 1024)
  int blocks = (n + 256*PPT - 1) / (256*PPT);
  blocks = (blocks + 255) & ~255;
  hipLaunchKernelGGL(ffjord_main, dim3(blocks), dim3(256), 0, stream,
                     z1, ws, out, n,
                     cf[0], cf[1], cf[2], cf[3], cf[4], cf[5], cf[6]);
}

// Round 6
// 93.718 us; speedup vs baseline: 1.2361x; 1.0988x over previous
//
#include <hip/hip_runtime.h>
#include <math.h>
#include <string.h>
#include <stdint.h>

#define NB 32      // BF
#define NW 32      // WIDTH
#define PS2 132    // uint words per stage: 16 iters * 8 words + S + pad (528B, 16B-aligned)
#define PPT 4      // points per thread

typedef _Float16 h2 __attribute__((ext_vector_type(2)));

// Stage layout (uint words), iteration i in [0,16) covers units (i, i+16).
// word[i*8+0..2] = h2{ W[i][d]/3,  W[i+16][d]/3 }   d=0,1,2
// word[i*8+3]    = h2{ Bb[i]/3,    Bb[i+16]/3 }
// word[i*8+4..6] = h2{ U''[i][d],  U''[i+16][d] }   U'' = U*sigmoid(G)/32
// word[i*8+7]    = h2{ s'[i],      s'[i+16] }       s' = (1/32)*sum_d W*U'sig
// word[128]      = f32 S = sum_w (float)f16(s'[w])

__device__ __forceinline__ uint32_t pk2(float lo, float hi) {
  unsigned short a = __builtin_bit_cast(unsigned short, (_Float16)lo);
  unsigned short b = __builtin_bit_cast(unsigned short, (_Float16)hi);
  return (uint32_t)a | ((uint32_t)b << 16);
}

__global__ void hyper_kernel(const float* __restrict__ w1, const float* __restrict__ b1,
                             const float* __restrict__ w2, const float* __restrict__ b2,
                             const float* __restrict__ wW, const float* __restrict__ bW,
                             const float* __restrict__ wU, const float* __restrict__ bU,
                             const float* __restrict__ wG, const float* __restrict__ bG,
                             const float* __restrict__ wB, const float* __restrict__ bB,
                             uint32_t* __restrict__ ws) {
  const int stage = blockIdx.x;
  const float tv[8] = {2.f, 1.5f, 1.5f, 1.f, 1.f, 0.5f, 0.5f, 0.f};
  const float t = tv[stage];
  __shared__ float h1[NB], h2s[NB];
  __shared__ float Wl[NW*3], Ul[NW*3], Gl[NW*3], UUl[NW*3], Bbl[NW], sl[NW];
  const int tid = threadIdx.x;

  if (tid < NB) h1[tid] = tanhf(t * w1[tid] + b1[tid]);
  __syncthreads();
  if (tid < NB) {
    float a = b2[tid];
    for (int j = 0; j < NB; ++j) a = fmaf(w2[tid*NB + j], h1[j], a);
    h2s[tid] = tanhf(a);
  }
  __syncthreads();
  for (int idx = tid; idx < 3*NW*3 + NW; idx += blockDim.x) {
    if (idx < 96) {
      float a = bW[idx];
      for (int j = 0; j < NB; ++j) a = fmaf(wW[idx*NB + j], h2s[j], a);
      Wl[idx] = a;
    } else if (idx < 192) {
      int i = idx - 96; float a = bU[i];
      for (int j = 0; j < NB; ++j) a = fmaf(wU[i*NB + j], h2s[j], a);
      Ul[i] = a;
    } else if (idx < 288) {
      int i = idx - 192; float a = bG[i];
      for (int j = 0; j < NB; ++j) a = fmaf(wG[i*NB + j], h2s[j], a);
      Gl[i] = a;
    } else {
      int i = idx - 288; float a = bB[i];
      for (int j = 0; j < NB; ++j) a = fmaf(wB[i*NB + j], h2s[j], a);
      Bbl[i] = a;
    }
  }
  __syncthreads();
  for (int idx = tid; idx < NW*3; idx += blockDim.x)
    UUl[idx] = Ul[idx] / (1.f + expf(-Gl[idx]));
  __syncthreads();
  if (tid < NW)
    sl[tid] = Wl[3*tid+0]*UUl[3*tid+0] + Wl[3*tid+1]*UUl[3*tid+1] + Wl[3*tid+2]*UUl[3*tid+2];
  __syncthreads();

  uint32_t* o = ws + stage * PS2;
  const float inv = 1.f / 32.f;
  const float i3  = 1.f / 3.f;
  if (tid < 16) {
    const int i = tid, k = tid + 16;
    o[i*8+0] = pk2(i3*Wl[3*i+0],   i3*Wl[3*k+0]);
    o[i*8+1] = pk2(i3*Wl[3*i+1],   i3*Wl[3*k+1]);
    o[i*8+2] = pk2(i3*Wl[3*i+2],   i3*Wl[3*k+2]);
    o[i*8+3] = pk2(i3*Bbl[i],      i3*Bbl[k]);
    o[i*8+4] = pk2(inv*UUl[3*i+0], inv*UUl[3*k+0]);
    o[i*8+5] = pk2(inv*UUl[3*i+1], inv*UUl[3*k+1]);
    o[i*8+6] = pk2(inv*UUl[3*i+2], inv*UUl[3*k+2]);
    o[i*8+7] = pk2(inv*sl[i],      inv*sl[k]);
  }
  __syncthreads();
  if (tid == 0) {
    float S = 0.f;
    for (int w = 0; w < NW; ++w) S += (float)(_Float16)(inv * sl[w]);
    o[128] = __builtin_bit_cast(uint32_t, S);
  }
}

__device__ __forceinline__ h2 hfma(h2 a, h2 b, h2 c) { return __builtin_elementwise_fma(a, b, c); }
__device__ __forceinline__ h2 bch(float x) { _Float16 h = (_Float16)x; h2 r; r.x = h; r.y = h; return r; }

__global__ __launch_bounds__(256) void ffjord_main(const float* __restrict__ z1,
                                                   const uint32_t* __restrict__ wsu,
                                                   float* __restrict__ out, int n,
                                                   float c0, float c1, float c2, float c3,
                                                   float c4, float c5, float c6) {
  __shared__ __align__(16) uint32_t sp[8*PS2];
  for (int i = threadIdx.x; i < 8*PS2; i += 256) sp[i] = wsu[i];
  __syncthreads();

  // duplicated f16 constants (hoisted)
  const h2 C0 = bch(c0), C1 = bch(c1), C2 = bch(c2), C3 = bch(c3),
           C4 = bch(c4), C5 = bch(c5), C6 = bch(c6);
  const h2 ONE = bch(1.f), MONE = bch(-1.f), TWO = bch(2.f);

  const int base    = blockIdx.x * 256 + threadIdx.x;
  const int pstride = gridDim.x * 256;

  float zx[PPT], zy[PPT], zz[PPT], ld[PPT];
  bool val[PPT];
#pragma unroll
  for (int j = 0; j < PPT; ++j) {
    int i = base + j * pstride;
    val[j] = (i < n);
    int ii = val[j] ? i : 0;
    zx[j] = z1[3*ii+0]; zy[j] = z1[3*ii+1]; zz[j] = z1[3*ii+2];
    ld[j] = 0.f;
  }

  for (int itv = 0; itv < 2; ++itv) {
    float accx[PPT], accy[PPT], accz[PPT], acct[PPT];
    float kx[PPT], ky[PPT], kz[PPT];
#pragma unroll
    for (int j = 0; j < PPT; ++j) {
      accx[j]=0.f; accy[j]=0.f; accz[j]=0.f; acct[j]=0.f;
      kx[j]=0.f; ky[j]=0.f; kz[j]=0.f;
    }
    for (int s = 0; s < 4; ++s) {
      const float as = (s == 0) ? 0.f : ((s == 3) ? -1.f : -0.5f);
      const float bs = (s == 1 || s == 2) ? 2.f : 1.f;
      const uint32_t* st = sp + (itv*4 + s) * PS2;
      const float S = __builtin_bit_cast(float, st[128]);
      const uint4* q = reinterpret_cast<const uint4*>(st);

      // stage input, packed f16 (dup across halves), state stays f32
      h2 yx2[PPT], yy2[PPT], yz2[PPT];
#pragma unroll
      for (int j = 0; j < PPT; ++j) {
        yx2[j] = bch(fmaf(as, kx[j], zx[j]));
        yy2[j] = bch(fmaf(as, ky[j], zy[j]));
        yz2[j] = bch(fmaf(as, kz[j], zz[j]));
      }
      h2 ax2[PPT], ay2[PPT], az2[PPT], a22[PPT];
#pragma unroll
      for (int j = 0; j < PPT; ++j) { ax2[j]=bch(0.f); ay2[j]=bch(0.f); az2[j]=bch(0.f); a22[j]=bch(0.f); }

#pragma unroll
      for (int it = 0; it < 16; ++it) {
        const uint4 A  = q[2*it];     // W/3 (x,y,z), Bb/3 — units (it, it+16) in halves
        const uint4 Bv = q[2*it+1];   // U'' (x,y,z), s'
        const h2 Ax = __builtin_bit_cast(h2, A.x),  Ay = __builtin_bit_cast(h2, A.y);
        const h2 Az = __builtin_bit_cast(h2, A.z),  Ab = __builtin_bit_cast(h2, A.w);
        const h2 Bx = __builtin_bit_cast(h2, Bv.x), By = __builtin_bit_cast(h2, Bv.y);
        const h2 Bz = __builtin_bit_cast(h2, Bv.z), Bs = __builtin_bit_cast(h2, Bv.w);
#pragma unroll
        for (int j = 0; j < PPT; ++j) {
          h2 wv = hfma(yx2[j], Ax, hfma(yy2[j], Ay, hfma(yz2[j], Az, Ab)));
          wv = __builtin_elementwise_min(__builtin_elementwise_max(wv, MONE), ONE);
          h2 t = wv * wv;
          h2 u = hfma(t, TWO, MONE);          // u = 2t-1 in [-1,1]
          h2 P = hfma(C6, u, C5);
          P = hfma(P, u, C4);
          P = hfma(P, u, C3);
          P = hfma(P, u, C2);
          P = hfma(P, u, C1);
          P = hfma(P, u, C0);
          h2 h = wv * P;                       // tanh(3*wv)
          ax2[j] = hfma(h, Bx, ax2[j]);
          ay2[j] = hfma(h, By, ay2[j]);
          az2[j] = hfma(h, Bz, az2[j]);
          a22[j] = hfma(h*h, Bs, a22[j]);
        }
      }
      // unpack (sum unit-halves), accumulate RK4 in f32
#pragma unroll
      for (int j = 0; j < PPT; ++j) {
        kx[j] = (float)ax2[j].x + (float)ax2[j].y;
        ky[j] = (float)ay2[j].x + (float)ay2[j].y;
        kz[j] = (float)az2[j].x + (float)az2[j].y;
        float kt = S - ((float)a22[j].x + (float)a22[j].y);
        accx[j] = fmaf(bs, kx[j], accx[j]);
        accy[j] = fmaf(bs, ky[j], accy[j]);
        accz[j] = fmaf(bs, kz[j], accz[j]);
        acct[j] = fmaf(bs, kt,    acct[j]);
      }
    }
    const float c = 1.f / 6.f;
#pragma unroll
    for (int j = 0; j < PPT; ++j) {
      zx[j] -= c * accx[j];
      zy[j] -= c * accy[j];
      zz[j] -= c * accz[j];
      ld[j] -= c * acct[j];
    }
  }

#pragma unroll
  for (int j = 0; j < PPT; ++j) {
    if (val[j]) {
      int i = base + j * pstride;
      out[3*i+0] = zx[j]; out[3*i+1] = zy[j]; out[3*i+2] = zz[j];
      out[3*n + i] = ld[j];
    }
  }
}

// ---- host helpers: f16 RNE rounding + cascaded LS fit --------------------
static float rne16(float x) {
  uint32_t b; memcpy(&b, &x, 4);
  uint32_t lsb = 1u << 13, half = lsb >> 1, mask = lsb - 1;
  uint32_t frac = b & mask;
  b &= ~mask;
  if (frac > half || (frac == half && (b & lsb))) b += lsb;
  float r; memcpy(&r, &b, 4); return r;
}

static void solve_ls(int m, double A[7][7], double* bv, double* sol) {
  for (int c = 0; c < m; ++c) {
    int p = c;
    for (int r = c+1; r < m; ++r) if (fabs(A[r][c]) > fabs(A[p][c])) p = r;
    for (int j = 0; j < m; ++j) { double t = A[c][j]; A[c][j] = A[p][j]; A[p][j] = t; }
    { double t = bv[c]; bv[c] = bv[p]; bv[p] = t; }
    for (int r = c+1; r < m; ++r) {
      double f = A[r][c] / A[c][c];
      for (int j = c; j < m; ++j) A[r][j] -= f * A[c][j];
      bv[r] -= f * bv[c];
    }
  }
  for (int r = m-1; r >= 0; --r) {
    double s = bv[r];
    for (int j = r+1; j < m; ++j) s -= A[r][j] * sol[j];
    sol[r] = s / A[r][r];
  }
}

extern "C" void kernel_launch(void* const* d_in, const int* in_sizes, int n_in,
                              void* d_out, int out_size, void* d_ws, size_t ws_size,
                              hipStream_t stream) {
  const float* z1 = (const float*)d_in[0];
  const float* w1 = (const float*)d_in[1];
  const float* b1 = (const float*)d_in[2];
  const float* w2 = (const float*)d_in[3];
  const float* b2 = (const float*)d_in[4];
  const float* wW = (const float*)d_in[5];
  const float* bW = (const float*)d_in[6];
  const float* wU = (const float*)d_in[7];
  const float* bU = (const float*)d_in[8];
  const float* wG = (const float*)d_in[9];
  const float* bG = (const float*)d_in[10];
  const float* wB = (const float*)d_in[11];
  const float* bB = (const float*)d_in[12];
  float* out = (float*)d_out;
  uint32_t* ws = (uint32_t*)d_ws;
  const int n = in_sizes[0] / 3;

  // Host: fit Q(u) ~ tanh(3*sqrt(t))/sqrt(t), t=(u+1)/2, u in [-1,1], deg 6,
  // with cascaded f16 rounding: round the top coefficient, refit the residual
  // at one lower degree, repeat — coherent coefficient error ~1 ulp_f16.
  const int M = 257;
  double uu[M], resid[M];
  for (int m = 0; m < M; ++m) {
    uu[m] = -1.0 + 2.0 * m / (M - 1);
    double t = 0.5 * (uu[m] + 1.0);
    double w = sqrt(t);
    resid[m] = (t > 1e-12) ? tanh(3.0 * w) / w : 3.0;
  }
  float cf[7];
  for (int k = 6; k >= 0; --k) {
    double A[7][7], bv[7], sol[7];
    for (int i = 0; i <= k; ++i) { bv[i] = 0.0; for (int j = 0; j <= k; ++j) A[i][j] = 0.0; }
    for (int m = 0; m < M; ++m) {
      double pw[7]; pw[0] = 1.0;
      for (int i = 1; i <= k; ++i) pw[i] = pw[i-1] * uu[m];
      for (int i = 0; i <= k; ++i) {
        bv[i] += pw[i] * resid[m];
        for (int j = 0; j <= k; ++j) A[i][j] += pw[i] * pw[j];
      }
    }
    solve_ls(k+1, A, bv, sol);
    cf[k] = rne16((float)sol[k]);
    for (int m = 0; m < M; ++m) {
      double pk = 1.0;
      for (int i = 0; i < k; ++i) pk *= uu[m];
      resid[m] -= (double)cf[k] * pk;
    }
  }

  hipLaunchKernelGGL(hyper_kernel, dim3(8), dim3(128), 0, stream,
                     w1, b1, w2, b2, wW, bW, wU, bU, wG, bG, wB, bB, ws);
  int blocks = (n + 256*PPT - 1) / (256*PPT);
  blocks = (blocks + 255) & ~255;   // round to multiple of 256 CUs for balance
  hipLaunchKernelGGL(ffjord_main, dim3(blocks), dim3(256), 0, stream,
                     z1, ws, out, n,
                     cf[0], cf[1], cf[2], cf[3], cf[4], cf[5], cf[6]);
}